// Round 4
// baseline (115.690 us; speedup 1.0000x reference)
//
#include <hip/hip_runtime.h>
#include <stdint.h>

// Problem constants (B,C,H,W)=(4,128,64,128), R=4, D=9, out channels 81.
// out[b, di*9+dj, h, w] = sum_c src[b,c,h,w] * tgt[b,c,h+di-8,w+dj-8]
// (zero when the shifted index leaves [0,H)x[0,W)).
#define NB 4
#define NC 128
#define NH 64
#define NW 128
#define HW (NH * NW)      // 8192
#define ND 9
#define NOUT (ND * ND)    // 81
#define CPW 32            // channels per wave (4 waves x 32 = 128)
#define DT 3              // di values folded per block

// v5: di-folding to cut far-memory traffic. v1/v3/v4 all ~93us; rocprof
// shows the kernel itself is <43us and ~295 MB of far reads (9x redundant
// over 33.6 MB unique) are the H1 bottleneck candidate. One block now
// computes 3 consecutive di: src row-pair read once (was 3x) and 4 tgt
// rows serve 3 windows (was 6 rows across 3 blocks) -> ~148 MB far reads.
// grid = 4*3*32 = 384 blocks of 256 threads (4 waves):
//   g>>5 = q: b = q/3, d0 = (q%3)*3 ; hp = g&31
//   h = hp*2 + (lane>>5), w0 = (lane&31)*4; wave owns 32 channels.
// Row validity (y = h+d0+dt-8 >= 0) handled by loop-invariant AND masks
// folded into the window edge masks; bpermutes run unconditionally under
// full exec (v2 lesson: guarded bpermute disables source lanes).
__device__ __forceinline__ float pull_and(int byteidx, float v, int m) {
  return __int_as_float(__builtin_amdgcn_ds_bpermute(byteidx, __float_as_int(v)) & m);
}

__global__ __launch_bounds__(256, 2) void costvol_kernel(const float* __restrict__ src,
                                                         const float* __restrict__ tgt,
                                                         float* __restrict__ out) {
  const int tid  = threadIdx.x;
  const int lane = tid & 63;
  const int wave = tid >> 6;

  const int g  = blockIdx.x;
  const int hp = g & 31;                   // 0..31
  const int q  = g >> 5;                   // 0..11
  const int b  = q / 3;                    // 0..3
  const int d0 = (q % 3) * DT;             // 0,3,6

  const int h  = (hp << 1) + (lane >> 5);  // 0..63
  const int w0 = (lane & 31) << 2;         // 0,4,...,124
  const int ybase = h + d0 - 8;            // tgt row for dt=0

  float acc[DT][ND][4];
#pragma unroll
  for (int dt = 0; dt < DT; ++dt)
#pragma unroll
    for (int dj = 0; dj < ND; ++dj)
#pragma unroll
      for (int k = 0; k < 4; ++k) acc[dt][dj][k] = 0.0f;

  // Window-edge masks (quads at w0-8 / w0-4 all-in or all-out of bounds)
  // combined with per-dt row-validity masks -> loop-invariant AND masks.
  const int m0 = (w0 >= 8) ? -1 : 0;
  const int m1 = (w0 >= 4) ? -1 : 0;
  const int i2 = ((lane - 2) & 63) << 2;   // pull t2 quad of lane-2
  const int i1 = ((lane - 1) & 63) << 2;   // pull t2 quad of lane-1

  int ma[DT], mb[DT], mc[DT];              // t0-, t1-, t2-quad masks per dt
  const float* tp[DT];
#pragma unroll
  for (int dt = 0; dt < DT; ++dt) {
    const int y  = ybase + dt;
    const int mr = (y >= 0) ? -1 : 0;      // whole-row validity
    const int yc = (y >= 0) ? y : 0;       // clamped (loads stay in-bounds)
    ma[dt] = m0 & mr;
    mb[dt] = m1 & mr;
    mc[dt] = mr;
    tp[dt] = tgt + (size_t)((b * NC + wave * CPW) * NH + yc) * NW + w0;
  }
  const float* spc = src + (size_t)((b * NC + wave * CPW) * NH + h) * NW + w0;

#pragma unroll 2
  for (int c = 0; c < CPW; ++c) {
    const float4 sv = *(const float4*)spc;

#pragma unroll
    for (int dt = 0; dt < DT; ++dt) {
      const float4 r = *(const float4*)tp[dt];   // row y (clamped), cols w0..w0+3

      float t[12];
      // t0 quad (cols w0-8..w0-5) = r of lane-2; t1 = r of lane-1.
      // In-half pulls read the same tgt row (same dt, same lane-half);
      // cross-half/wrapped pulls land only in masked (zeroed) results.
      t[0]  = pull_and(i2, r.x, ma[dt]);
      t[1]  = pull_and(i2, r.y, ma[dt]);
      t[2]  = pull_and(i2, r.z, ma[dt]);
      t[3]  = pull_and(i2, r.w, ma[dt]);
      t[4]  = pull_and(i1, r.x, mb[dt]);
      t[5]  = pull_and(i1, r.y, mb[dt]);
      t[6]  = pull_and(i1, r.z, mb[dt]);
      t[7]  = pull_and(i1, r.w, mb[dt]);
      t[8]  = __int_as_float(__float_as_int(r.x) & mc[dt]);
      t[9]  = __int_as_float(__float_as_int(r.y) & mc[dt]);
      t[10] = __int_as_float(__float_as_int(r.z) & mc[dt]);
      t[11] = __int_as_float(__float_as_int(r.w) & mc[dt]);

#pragma unroll
      for (int dj = 0; dj < ND; ++dj) {
        acc[dt][dj][0] = fmaf(sv.x, t[dj + 0], acc[dt][dj][0]);
        acc[dt][dj][1] = fmaf(sv.y, t[dj + 1], acc[dt][dj][1]);
        acc[dt][dj][2] = fmaf(sv.z, t[dj + 2], acc[dt][dj][2]);
        acc[dt][dj][3] = fmaf(sv.w, t[dj + 3], acc[dt][dj][3]);
      }
      tp[dt] += HW;
    }
    spc += HW;
  }

  // Cross-wave reduction, one pass per dt reusing a 36 KB LDS buffer.
  __shared__ float lds[4][ND][64][4];
#pragma unroll
  for (int dt = 0; dt < DT; ++dt) {
    if (dt) __syncthreads();               // previous pass's readers done
#pragma unroll
    for (int dj = 0; dj < ND; ++dj) {
      float4 v;
      v.x = acc[dt][dj][0]; v.y = acc[dt][dj][1];
      v.z = acc[dt][dj][2]; v.w = acc[dt][dj][3];
      *(float4*)&lds[wave][dj][lane][0] = v;
    }
    __syncthreads();

    const int di = d0 + dt;
    for (int s = tid; s < ND * 64; s += 256) {
      const int dj = s >> 6;
      const int l  = s & 63;
      const float4 r0 = *(const float4*)&lds[0][dj][l][0];
      const float4 r1 = *(const float4*)&lds[1][dj][l][0];
      const float4 r2 = *(const float4*)&lds[2][dj][l][0];
      const float4 r3 = *(const float4*)&lds[3][dj][l][0];
      float4 o;
      o.x = (r0.x + r1.x) + (r2.x + r3.x);
      o.y = (r0.y + r1.y) + (r2.y + r3.y);
      o.z = (r0.z + r1.z) + (r2.z + r3.z);
      o.w = (r0.w + r1.w) + (r2.w + r3.w);
      const int hh = (hp << 1) + (l >> 5);
      const int ww = (l & 31) << 2;
      *(float4*)(out + (size_t)(((b * NOUT + di * ND + dj) * NH + hh) * NW + ww)) = o;
    }
  }
}

extern "C" void kernel_launch(void* const* d_in, const int* in_sizes, int n_in,
                              void* d_out, int out_size, void* d_ws, size_t ws_size,
                              hipStream_t stream) {
  const float* src = (const float*)d_in[0];
  const float* tgt = (const float*)d_in[1];
  float* out = (float*)d_out;
  costvol_kernel<<<dim3(NB * DT * 32), dim3(256), 0, stream>>>(src, tgt, out);
}

// Round 5
// 106.754 us; speedup vs baseline: 1.0837x; 1.0837x over previous
//
#include <hip/hip_runtime.h>
#include <stdint.h>

// Problem constants (B,C,H,W)=(4,128,64,128), R=4, D=9, out channels 81.
// out[b, di*9+dj, h, w] = sum_c src[b,c,h,w] * tgt[b,c,h+di-8,w+dj-8]
// (zero when the shifted index leaves [0,H)x[0,W); shifts are [-8,0]).
#define NB 4
#define NC 128
#define NH 64
#define NW 128
#define HW (NH * NW)      // 8192
#define ND 9
#define NOUT (ND * ND)    // 81
#define DT 3              // di values folded per block
#define CPW 16            // channels per wave (8 waves x 16 = 128)

// v6: DT=3 fold kept (far traffic ~148 MB vs v3's 295), occupancy restored.
// R4 profile: v5 = 61us, Occ 12.7%, VALUBusy 15.9%, FETCH 46 MB -> purely
// latency-bound at 1.5 blocks/CU; HBM is NOT the limit. v6: 2 floats/lane
// (wave = one full 512B row), acc[3][9][2]=54 VGPR, 512-thread blocks
// (8 waves x 16ch, LDS tree reduce), grid = 4b*3dg*64h = 768 blocks ->
// 24 waves/CU offered (~16 resident at ~105 VGPR) vs v5's 4-6.
// Row validity: pre-mask the loaded pair by the row mask once; neighbor
// pulls then see already-zeroed values (bpermutes stay unconditional under
// full exec — v2 lesson). Left-edge: per-source-lane masks on pull results.
// XCD decode: xcd=g&7 owns h-octant; 3 dg-sharers of (b,h) adjacent in j.
__device__ __forceinline__ float bperm(int byteidx, float v) {
  return __int_as_float(__builtin_amdgcn_ds_bpermute(byteidx, __float_as_int(v)));
}
__device__ __forceinline__ float fand(float v, int m) {
  return __int_as_float(__float_as_int(v) & m);
}

__global__ __launch_bounds__(512, 4) void costvol_kernel(const float* __restrict__ src,
                                                         const float* __restrict__ tgt,
                                                         float* __restrict__ out) {
  const int tid  = threadIdx.x;
  const int lane = tid & 63;
  const int wave = tid >> 6;

  // grid 768 = 8 xcd * 96. j = b*24 + hlow*3 + dg (dg fastest: the 3
  // dg-sharers of a (b,h) row launch adjacently on the same XCD).
  const int xcd  = blockIdx.x & 7;
  const int j    = blockIdx.x >> 3;        // 0..95
  const int b    = j / 24;                 // 0..3
  const int rr   = j % 24;
  const int hlow = rr / 3;                 // 0..7
  const int dg   = rr % 3;                 // 0..2
  const int h    = (xcd << 3) | hlow;      // 0..63
  const int d0   = dg * DT;                // 0,3,6

  const int w0 = lane << 1;                // 0,2,...,126
  const int c0 = wave * CPW;               // wave's channel base

  float acc[DT][ND][2];
#pragma unroll
  for (int dt = 0; dt < DT; ++dt)
#pragma unroll
    for (int dj = 0; dj < ND; ++dj) { acc[dt][dj][0] = 0.f; acc[dt][dj][1] = 0.f; }

  // Left-edge masks: source lane-k (k=1..4) supplies cols w0-2k, w0-2k+1,
  // valid iff lane >= k. Row masks mr[dt] pre-applied to the loaded pair.
  const int m1 = (lane >= 1) ? -1 : 0;
  const int m2 = (lane >= 2) ? -1 : 0;
  const int m3 = (lane >= 3) ? -1 : 0;
  const int m4 = (lane >= 4) ? -1 : 0;
  const int i1 = ((lane - 1) & 63) << 2;
  const int i2 = ((lane - 2) & 63) << 2;
  const int i3 = ((lane - 3) & 63) << 2;
  const int i4 = ((lane - 4) & 63) << 2;

  int mr[DT];
  const float* tp[DT];
#pragma unroll
  for (int dt = 0; dt < DT; ++dt) {
    const int y = h + d0 + dt - 8;         // tgt row; <0 -> masked to zero
    mr[dt] = (y >= 0) ? -1 : 0;
    const int yc = (y >= 0) ? y : 0;       // clamped: loads stay in-bounds
    tp[dt] = tgt + (size_t)((b * NC + c0) * NH + yc) * NW + w0;
  }
  const float* sp = src + (size_t)((b * NC + c0) * NH + h) * NW + w0;

#pragma unroll 2
  for (int c = 0; c < CPW; ++c) {
    const float2 sv = *(const float2*)sp;

#pragma unroll
    for (int dt = 0; dt < DT; ++dt) {
      float2 r = *(const float2*)tp[dt];   // cols w0,w0+1 of row y (clamped)
      r.x = fand(r.x, mr[dt]);             // row-invalid -> 0 before sharing
      r.y = fand(r.y, mr[dt]);

      // t[jj] = tgt col w0-8+jj, jj=0..9. lane-k supplies t[8-2k],t[9-2k].
      float t[10];
      t[0] = fand(bperm(i4, r.x), m4);
      t[1] = fand(bperm(i4, r.y), m4);
      t[2] = fand(bperm(i3, r.x), m3);
      t[3] = fand(bperm(i3, r.y), m3);
      t[4] = fand(bperm(i2, r.x), m2);
      t[5] = fand(bperm(i2, r.y), m2);
      t[6] = fand(bperm(i1, r.x), m1);
      t[7] = fand(bperm(i1, r.y), m1);
      t[8] = r.x;
      t[9] = r.y;

#pragma unroll
      for (int dj = 0; dj < ND; ++dj) {
        acc[dt][dj][0] = fmaf(sv.x, t[dj],     acc[dt][dj][0]);
        acc[dt][dj][1] = fmaf(sv.y, t[dj + 1], acc[dt][dj][1]);
      }
      tp[dt] += HW;
    }
    sp += HW;
  }

  // Cross-wave reduction over 8 waves (channel chunks), one pass per dt.
  // lds[8][9][64] float2 = 36 KB.
  __shared__ float2 lds[8][ND][64];
#pragma unroll
  for (int dt = 0; dt < DT; ++dt) {
    if (dt) __syncthreads();               // previous pass's readers done
#pragma unroll
    for (int dj = 0; dj < ND; ++dj)
      lds[wave][dj][lane] = make_float2(acc[dt][dj][0], acc[dt][dj][1]);
    __syncthreads();

    const int di = d0 + dt;
    for (int s = tid; s < ND * 64; s += 512) {
      const int dj = s >> 6;
      const int l  = s & 63;
      float2 a0 = lds[0][dj][l], a1 = lds[1][dj][l];
      float2 a2 = lds[2][dj][l], a3 = lds[3][dj][l];
      float2 a4 = lds[4][dj][l], a5 = lds[5][dj][l];
      float2 a6 = lds[6][dj][l], a7 = lds[7][dj][l];
      float2 o;
      o.x = ((a0.x + a1.x) + (a2.x + a3.x)) + ((a4.x + a5.x) + (a6.x + a7.x));
      o.y = ((a0.y + a1.y) + (a2.y + a3.y)) + ((a4.y + a5.y) + (a6.y + a7.y));
      *(float2*)(out + (size_t)((b * NOUT + di * ND + dj) * NH + h) * NW + (l << 1)) = o;
    }
  }
}

extern "C" void kernel_launch(void* const* d_in, const int* in_sizes, int n_in,
                              void* d_out, int out_size, void* d_ws, size_t ws_size,
                              hipStream_t stream) {
  const float* src = (const float*)d_in[0];
  const float* tgt = (const float*)d_in[1];
  float* out = (float*)d_out;
  costvol_kernel<<<dim3(NB * DT * 64), dim3(512), 0, stream>>>(src, tgt, out);
}

// Round 6
// 87.316 us; speedup vs baseline: 1.3250x; 1.2226x over previous
//
#include <hip/hip_runtime.h>
#include <stdint.h>

// Problem constants (B,C,H,W)=(4,128,64,128), R=4, D=9, out channels 81.
// out[b, di*9+dj, h, w] = sum_c src[b,c,h,w] * tgt[b,c,h+di-8,w+dj-8]
// (zero when the shifted index leaves [0,H)x[0,W); shifts are [-8,0]).
//
// v7: MFMA banded-Gram formulation. For each (b,h,di):
//   C[m=w, n=w'] = sum_c src[c,m] * tgt[c,n];  out[dj,w] = C[w, w+dj-8]
// Per 16-wide m-tile only 2 n-tiles intersect the 9-wide band: diag (n0=m0)
// and sub (n0=m0-16). Block=(b,h), 8 waves = 8 m-tiles; per di each wave
// does 8 MFMA (2 tiles x K=128 in 4 chunks of 32) via
// __builtin_amdgcn_mfma_f32_16x16x32_bf16.
// LDS K-panel layout [c>>3][n][c&7] (bf16) makes each A/B fragment one
// ds_read_b128 of 8 contiguous k (m92/m97-verified fragment pattern:
// lane l: row/col = l&15, k = 8*(l>>4)+j). Panel rows padded to 2080 B so
// the 4 lane-groups land on disjoint bank phases.
// Band extraction scatters into a swizzled 4.6 KB out-LDS tile; a store
// pass writes coalesced float4 with cndmask zeros for the w+dj<8 wedge and
// y<0 dead planes (no zero-init needed; stale slots are always masked).
#define NB 4
#define NC 128
#define NH 64
#define NW 128
#define HW (NH * NW)      // 8192
#define ND 9
#define NOUT (ND * ND)    // 81
#define PROW 1040         // halfwords per k-oct panel row (16 n-tiles worth)

typedef __attribute__((ext_vector_type(8))) short short8;
typedef __attribute__((ext_vector_type(4))) float f32x4;

__device__ __forceinline__ ushort f2bf(float f) {  // RNE f32->bf16
  uint u = __float_as_uint(f);
  u += 0x7FFFu + ((u >> 16) & 1u);
  return (ushort)(u >> 16);
}

__global__ __launch_bounds__(512, 2) void costvol_kernel(const float* __restrict__ src,
                                                         const float* __restrict__ tgt,
                                                         float* __restrict__ out) {
  __shared__ ushort srcP[16 * PROW];      // 33.3 KB, src row h, K-panel
  __shared__ ushort tgtP[2][16 * PROW];   // 66.5 KB, tgt row double-buffer
  __shared__ float  outlds[ND * NW];      // 4.6 KB, one di's (dj,w) tile

  const int tid  = threadIdx.x;
  const int lane = tid & 63;
  const int wave = tid >> 6;              // 0..7 = m-tile
  const int col  = lane & 15;             // fragment col/row index
  const int g    = lane >> 4;             // k-group

  // XCD-pinned decode: xcd owns (b = xcd>>1, h-half = xcd&1); h-contiguous
  // blocks (which share tgt rows) stay on one XCD's L2. 256 blocks = 1/CU.
  const int xcd = blockIdx.x & 7;
  const int b   = xcd >> 1;
  const int h   = ((xcd & 1) << 5) | (blockIdx.x >> 3);

  // staging coords: thread owns an 8c x 4n tile of the 128x128 row
  const int sc = (tid >> 5) << 3;         // c-oct base 0..120
  const int sn = (tid & 31) << 2;         // n base 0..124

  const float* sbase = src + (size_t)(b * NC) * HW;
  const float* tbase = tgt + (size_t)(b * NC) * HW;

  // ---- prologue: stage src panel (row h) and tgt row for di=0 ----
  {
    float4 v[8];
#pragma unroll
    for (int j = 0; j < 8; ++j)
      v[j] = *(const float4*)(sbase + (size_t)(sc + j) * HW + h * NW + sn);
#pragma unroll
    for (int i = 0; i < 4; ++i) {
      short8 e;
#pragma unroll
      for (int j = 0; j < 8; ++j) e[j] = (short)f2bf(((const float*)&v[j])[i]);
      *(short8*)&srcP[(tid >> 5) * PROW + (sn + i) * 8] = e;
    }
  }
  {
    const int y0 = (h - 8 < 0) ? 0 : (h - 8);
    float4 v[8];
#pragma unroll
    for (int j = 0; j < 8; ++j)
      v[j] = *(const float4*)(tbase + (size_t)(sc + j) * HW + y0 * NW + sn);
#pragma unroll
    for (int i = 0; i < 4; ++i) {
      short8 e;
#pragma unroll
      for (int j = 0; j < 8; ++j) e[j] = (short)f2bf(((const float*)&v[j])[i]);
      *(short8*)&tgtP[0][(tid >> 5) * PROW + (sn + i) * 8] = e;
    }
  }
  __syncthreads();

  // ---- A fragments: src m-tile, K=128 in 4 chunks (held in 16 VGPRs) ----
  const int m0 = wave << 4;
  short8 A[4];
#pragma unroll
  for (int kk = 0; kk < 4; ++kk)
    A[kk] = *(const short8*)&srcP[(4 * kk + g) * PROW + (m0 + col) * 8];

  for (int di = 0; di < ND; ++di) {
    const int p = di & 1;
    const int y = h + di - 8;             // tgt row of this di; <0 -> zeros

    // issue next tgt row's global loads early (land under the MFMA phase)
    float4 v[8];
    const bool havenext = (di < 8);
    if (havenext) {
      const int yn = (y + 1 < 0) ? 0 : (y + 1);
#pragma unroll
      for (int j = 0; j < 8; ++j)
        v[j] = *(const float4*)(tbase + (size_t)(sc + j) * HW + yn * NW + sn);
    }

    if (y >= 0) {
      const ushort* tp = tgtP[p];
      short8 BD[4], BS[4];
#pragma unroll
      for (int kk = 0; kk < 4; ++kk)
        BD[kk] = *(const short8*)&tp[(4 * kk + g) * PROW + (m0 + col) * 8];
      if (wave) {
#pragma unroll
        for (int kk = 0; kk < 4; ++kk)
          BS[kk] = *(const short8*)&tp[(4 * kk + g) * PROW + (m0 - 16 + col) * 8];
      }

      f32x4 accD = {0.f, 0.f, 0.f, 0.f};
      f32x4 accS = {0.f, 0.f, 0.f, 0.f};
#pragma unroll
      for (int kk = 0; kk < 4; ++kk)
        accD = __builtin_amdgcn_mfma_f32_16x16x32_bf16(A[kk], BD[kk], accD, 0, 0, 0);
      if (wave) {
#pragma unroll
        for (int kk = 0; kk < 4; ++kk)
          accS = __builtin_amdgcn_mfma_f32_16x16x32_bf16(A[kk], BS[kk], accS, 0, 0, 0);
      }

      // band extraction: C/D layout col=lane&15, row=4*(lane>>4)+reg (m89).
      // diag: dj = col-row+8 ; sub: dj = col-row-8. Swizzled out-LDS index
      // dj*128 + ((w+4*dj)&127) spreads the 512B dj-stride across banks.
#pragma unroll
      for (int q = 0; q < 4; ++q) {
        const int row = 4 * g + q;
        const int w   = m0 + row;
        const int djd = col - row + 8;
        if (djd >= 0 && djd <= 8)
          outlds[djd * NW + ((w + 4 * djd) & 127)] = accD[q];
        if (wave) {
          const int djs = col - row - 8;
          if (djs >= 0 && djs <= 8)
            outlds[djs * NW + ((w + 4 * djs) & 127)] = accS[q];
        }
      }
    }

    // finish staging into the OTHER buffer (no barrier needed before this)
    if (havenext) {
#pragma unroll
      for (int i = 0; i < 4; ++i) {
        short8 e;
#pragma unroll
        for (int j = 0; j < 8; ++j) e[j] = (short)f2bf(((const float*)&v[j])[i]);
        *(short8*)&tgtP[p ^ 1][(tid >> 5) * PROW + (sn + i) * 8] = e;
      }
    }

    __syncthreads();   // scatter + staging done

    // store pass: 9 dj-rows x 128 w, coalesced float4; zeros for the
    // w+dj<8 wedge and whole y<0 planes (stale outlds slots never leak).
    if (tid < ND * 32) {
      const int dj = tid >> 5;
      const int w  = (tid & 31) << 2;
      f32x4 o = *(const f32x4*)&outlds[dj * NW + ((w + 4 * dj) & 127)];
      const bool vb = (y >= 0);
#pragma unroll
      for (int i = 0; i < 4; ++i)
        if (!vb || (w + i + dj < 8)) o[i] = 0.f;
      *(f32x4*)(out + ((size_t)((b * NOUT + di * ND + dj) * NH + h)) * NW + w) = o;
    }
    __syncthreads();   // outlds readers done before next di's scatter
  }
}

extern "C" void kernel_launch(void* const* d_in, const int* in_sizes, int n_in,
                              void* d_out, int out_size, void* d_ws, size_t ws_size,
                              hipStream_t stream) {
  const float* src = (const float*)d_in[0];
  const float* tgt = (const float*)d_in[1];
  float* out = (float*)d_out;
  costvol_kernel<<<dim3(NB * NH), dim3(512), 0, stream>>>(src, tgt, out);
}